// Round 1
// 626.925 us; speedup vs baseline: 1.0778x; 1.0778x over previous
//
#include <hip/hip_runtime.h>
#include <hip/hip_bf16.h>

// B=128, T=512, I=128, H=256, O=1 (fp32 in/out)
// xp = x @ W_ih^T + b_ih + b_hh  (fp32 in ws, 67.1 MB = proven size)
// h_t = tanh(xp_t + h @ W_hh^T)  via MFMA: D[n][b] = W_hh · h^T  (bf16 in, fp32 acc)
// out = sigmoid(h_T @ W_fc^T + b_fc)
//
// R1: rnn_kernel 256->512 threads (8 waves, 2 mt each) for 2 waves/SIMD TLP;
//     LDS pad 272->264 shorts (row-start bank = 4*(l15+quad) -> conflict-free b128 reads).

#define B_ 128
#define T_ 512
#define I_ 128
#define H_ 256
#define HP 264   // padded LDS row stride (shorts): stride/4 = 132 ≡ 4 (mod 32) -> conflict-free

typedef __attribute__((ext_vector_type(8))) short short8;
typedef __attribute__((ext_vector_type(4))) short short4v;
typedef __attribute__((ext_vector_type(4))) float floatx4;

__device__ __forceinline__ float tanh_fast(float x) {
    float e = __expf(2.0f * x);
    return 1.0f - 2.0f / (e + 1.0f);
}
__device__ __forceinline__ short f2bf(float f) {
    __hip_bfloat16 h = __float2bfloat16(f);   // RNE
    return *(short*)&h;
}

// ---------------- Kernel A: xp[m][n] via 16x16x32 bf16 MFMA, fp32 output.
// Block = 256 thr = 4 waves; tile 64(m) x 256(n). W_ih converted fp32->bf16
// inline at load (no convert kernel, no ws slot). Layouts verified round 3.
__global__ __launch_bounds__(256, 1)
void xp_mfma_kernel(const float* __restrict__ x, const float* __restrict__ W_ih,
                    const float* __restrict__ b_ih, const float* __restrict__ b_hh,
                    float* __restrict__ xp) {
    const int tid  = threadIdx.x;
    const int wave = tid >> 6, lane = tid & 63;
    const int l15  = lane & 15, quad = lane >> 4;
    const long m0 = (long)blockIdx.x * 64 + (wave & 1) * 32;
    const int  n0 = (wave >> 1) * 128;

    // B-operand (W_ih) fragments, fp32 loads -> bf16 pack, resident
    short8 bfrag[8][4];
#pragma unroll
    for (int nt = 0; nt < 8; ++nt)
#pragma unroll
        for (int kq = 0; kq < 4; ++kq) {
            const float* p = W_ih + (long)(n0 + nt * 16 + l15) * I_ + kq * 32 + quad * 8;
            float4 lo = *(const float4*)(p);
            float4 hi = *(const float4*)(p + 4);
            short8 f;
            f[0] = f2bf(lo.x); f[1] = f2bf(lo.y); f[2] = f2bf(lo.z); f[3] = f2bf(lo.w);
            f[4] = f2bf(hi.x); f[5] = f2bf(hi.y); f[6] = f2bf(hi.z); f[7] = f2bf(hi.w);
            bfrag[nt][kq] = f;
        }

    // A-operand (x) fragments
    short8 afrag[2][4];
#pragma unroll
    for (int mt = 0; mt < 2; ++mt)
#pragma unroll
        for (int kq = 0; kq < 4; ++kq) {
            const float* p = x + (m0 + mt * 16 + l15) * I_ + kq * 32 + quad * 8;
            float4 lo = *(const float4*)(p);
            float4 hi = *(const float4*)(p + 4);
            short8 f;
            f[0] = f2bf(lo.x); f[1] = f2bf(lo.y); f[2] = f2bf(lo.z); f[3] = f2bf(lo.w);
            f[4] = f2bf(hi.x); f[5] = f2bf(hi.y); f[6] = f2bf(hi.z); f[7] = f2bf(hi.w);
            afrag[mt][kq] = f;
        }

    floatx4 acc[2][8];
#pragma unroll
    for (int mt = 0; mt < 2; ++mt)
#pragma unroll
        for (int nt = 0; nt < 8; ++nt) acc[mt][nt] = (floatx4){0.f, 0.f, 0.f, 0.f};

#pragma unroll
    for (int kq = 0; kq < 4; ++kq)
#pragma unroll
        for (int mt = 0; mt < 2; ++mt)
#pragma unroll
            for (int nt = 0; nt < 8; ++nt)
                acc[mt][nt] = __builtin_amdgcn_mfma_f32_16x16x32_bf16(
                    afrag[mt][kq], bfrag[nt][kq], acc[mt][nt], 0, 0, 0);

    float biasv[8];
#pragma unroll
    for (int nt = 0; nt < 8; ++nt) {
        int n = n0 + nt * 16 + l15;
        biasv[nt] = b_ih[n] + b_hh[n];
    }
#pragma unroll
    for (int mt = 0; mt < 2; ++mt)
#pragma unroll
        for (int nt = 0; nt < 8; ++nt)
#pragma unroll
            for (int r = 0; r < 4; ++r) {
                long row = m0 + mt * 16 + quad * 4 + r;
                xp[row * H_ + n0 + nt * 16 + l15] = acc[mt][nt][r] + biasv[nt];
            }
}

// ---------------- Kernel B: MFMA recurrence, 8 blocks x 16 batches.
// Block = 512 thr = 8 waves; wave owns output cols [wave*32, wave*32+32).
// A-operand = W_hh rows (register-resident: 2 mt x 8 kq x 4 VGPR = 64 VGPR).
// B-operand = h_t from LDS (lane l15 = batch, ds_read_b128, conflict-free pad).
// D[row=n-in-tile, col=batch] -> tanh -> b64 write of h_{t+1}[batch][4n].
__global__ __launch_bounds__(512, 2)
void rnn_kernel(const float* __restrict__ xp, const float* __restrict__ W_hh,
                const float* __restrict__ W_fc, const float* __restrict__ b_fc,
                float* __restrict__ out) {
    __shared__ __align__(16) short hbuf[2][16][HP];   // h as bf16, padded rows
    const int tid  = threadIdx.x;
    const int wave = tid >> 6, lane = tid & 63;
    const int l15  = lane & 15, quad = lane >> 4;
    const int b0   = blockIdx.x * 16;
    const int n0   = wave * 32;

    // W_hh A-fragments: fp32 load -> bf16, resident across all 512 steps
    short8 wfrag[2][8];
#pragma unroll
    for (int mt = 0; mt < 2; ++mt)
#pragma unroll
        for (int kq = 0; kq < 8; ++kq) {
            const float* p = W_hh + (long)(n0 + mt * 16 + l15) * H_ + kq * 32 + quad * 8;
            float4 lo = *(const float4*)(p);
            float4 hi = *(const float4*)(p + 4);
            short8 f;
            f[0] = f2bf(lo.x); f[1] = f2bf(lo.y); f[2] = f2bf(lo.z); f[3] = f2bf(lo.w);
            f[4] = f2bf(hi.x); f[5] = f2bf(hi.y); f[6] = f2bf(hi.z); f[7] = f2bf(hi.w);
            wfrag[mt][kq] = f;
        }

    // zero both h buffers (h_0 = 0)
    {
        int* hz = (int*)hbuf;
#pragma unroll
        for (int i = tid; i < 2 * 16 * HP / 2; i += 512) hz[i] = 0;
    }
    __syncthreads();

    // xp: lane (l15=batch, quad) reads float4 at col n0 + mt*16 + quad*4
    const float* xpl = xp + (long)(b0 + l15) * T_ * H_ + n0 + quad * 4;
    float4 xv[2], xnext[2];
#pragma unroll
    for (int mt = 0; mt < 2; ++mt) xv[mt] = *(const float4*)(xpl + mt * 16);

    const int laneoff = l15 * HP + quad * 8;   // B-frag read offset within buffer

#pragma unroll 1
    for (int t = 0; t < T_; ++t) {
        // prefetch xp for t+1 (clamped) — consumed next iteration
        const long tn = (t + 1 < T_) ? (t + 1) : (T_ - 1);
#pragma unroll
        for (int mt = 0; mt < 2; ++mt)
            xnext[mt] = *(const float4*)(xpl + tn * H_ + mt * 16);

        // B-fragments: h_t rows from buf[t&1]
        const short* hb = &hbuf[t & 1][0][0];
        short8 hfrag[8];
#pragma unroll
        for (int kq = 0; kq < 8; ++kq)
            hfrag[kq] = *(const short8*)(hb + laneoff + kq * 32);

        floatx4 acc[2];
#pragma unroll
        for (int mt = 0; mt < 2; ++mt) acc[mt] = (floatx4){0.f, 0.f, 0.f, 0.f};
#pragma unroll
        for (int kq = 0; kq < 8; ++kq)
#pragma unroll
            for (int mt = 0; mt < 2; ++mt)
                acc[mt] = __builtin_amdgcn_mfma_f32_16x16x32_bf16(
                    wfrag[mt][kq], hfrag[kq], acc[mt], 0, 0, 0);

        // epilogue: tanh(acc + xp) -> bf16 -> h_{t+1}[batch=l15][n0+mt*16+quad*4 ..+4]
        short* wb = &hbuf[(t + 1) & 1][0][0];
#pragma unroll
        for (int mt = 0; mt < 2; ++mt) {
            short4v hw;
            hw[0] = f2bf(tanh_fast(acc[mt][0] + xv[mt].x));
            hw[1] = f2bf(tanh_fast(acc[mt][1] + xv[mt].y));
            hw[2] = f2bf(tanh_fast(acc[mt][2] + xv[mt].z));
            hw[3] = f2bf(tanh_fast(acc[mt][3] + xv[mt].w));
            *(short4v*)(wb + l15 * HP + n0 + mt * 16 + quad * 4) = hw;
        }
#pragma unroll
        for (int mt = 0; mt < 2; ++mt) xv[mt] = xnext[mt];
        __syncthreads();
    }

    // head: out[b] = sigmoid(b_fc + sum_n h_T[b][n] * W_fc[n]); h_T in buf[0]
    if (tid < 256) {
        const int bl = tid >> 4, seg = tid & 15;
        const short* hr = &hbuf[0][bl][seg * 16];
        float p = 0.0f;
#pragma unroll
        for (int i = 0; i < 16; ++i) {
            __hip_bfloat16 hv = *(const __hip_bfloat16*)(hr + i);
            p += __bfloat162float(hv) * W_fc[seg * 16 + i];
        }
#pragma unroll
        for (int off = 1; off < 16; off <<= 1) p += __shfl_xor(p, off);
        if (seg == 0) out[b0 + bl] = 1.0f / (1.0f + __expf(-(p + b_fc[0])));
    }
}

extern "C" void kernel_launch(void* const* d_in, const int* in_sizes, int n_in,
                              void* d_out, int out_size, void* d_ws, size_t ws_size,
                              hipStream_t stream) {
    const float* x    = (const float*)d_in[0];
    const float* W_ih = (const float*)d_in[1];
    const float* W_hh = (const float*)d_in[2];
    const float* b_ih = (const float*)d_in[3];
    const float* b_hh = (const float*)d_in[4];
    const float* W_fc = (const float*)d_in[5];
    const float* b_fc = (const float*)d_in[6];
    float* out = (float*)d_out;

    float* xp = (float*)d_ws;   // B*T*H fp32 = 67.1 MB (round-1-proven ws footprint)

    xp_mfma_kernel<<<(B_ * T_) / 64, 256, 0, stream>>>(x, W_ih, b_ih, b_hh, xp);
    rnn_kernel<<<B_ / 16, 512, 0, stream>>>(xp, W_hh, W_fc, b_fc, out);
}

// Round 2
// 531.496 us; speedup vs baseline: 1.2713x; 1.1795x over previous
//
#include <hip/hip_runtime.h>
#include <hip/hip_bf16.h>

// B=128, T=512, I=128, H=256, O=1 (fp32 in/out)
// xp = x @ W_ih^T + b_ih + b_hh  (fp32 in ws)
// h_t = tanh(xp_t + h @ W_hh^T)  via MFMA: D[n][b] = W_hh · h^T  (bf16 in, fp32 acc)
// out = sigmoid(h_T @ W_fc^T + b_fc)
//
// R2: rnn_kernel rework —
//   * XOR-swizzled LDS (row stride 256 shorts, block c^=(l15&7)) -> bank-floor reads+writes
//   * MFMA chain split 8->4 (two accs), acc0 seeded with xp (kills post-MFMA adds)
//   * paired bf16 cvt (__float22bfloat162_rn -> v_cvt_pk_bf16_f32)
//   * raw "s_waitcnt lgkmcnt(0); s_barrier" (no vmcnt drain; xp prefetch stays in flight)
//   * manual unroll-2 (static ping-pong buffers + xp regs)

#define B_ 128
#define T_ 512
#define I_ 128
#define H_ 256

typedef __attribute__((ext_vector_type(8))) short short8;
typedef __attribute__((ext_vector_type(4))) short short4v;
typedef __attribute__((ext_vector_type(4))) float floatx4;

__device__ __forceinline__ float tanh_fast(float x) {
    float e = __expf(2.0f * x);
    return 1.0f - 2.0f / (e + 1.0f);
}
__device__ __forceinline__ short f2bf(float f) {
    __hip_bfloat16 h = __float2bfloat16(f);   // RNE
    return *(short*)&h;
}

// ---------------- Kernel A: xp[m][n] via 16x16x32 bf16 MFMA, fp32 output. (unchanged)
__global__ __launch_bounds__(256, 1)
void xp_mfma_kernel(const float* __restrict__ x, const float* __restrict__ W_ih,
                    const float* __restrict__ b_ih, const float* __restrict__ b_hh,
                    float* __restrict__ xp) {
    const int tid  = threadIdx.x;
    const int wave = tid >> 6, lane = tid & 63;
    const int l15  = lane & 15, quad = lane >> 4;
    const long m0 = (long)blockIdx.x * 64 + (wave & 1) * 32;
    const int  n0 = (wave >> 1) * 128;

    short8 bfrag[8][4];
#pragma unroll
    for (int nt = 0; nt < 8; ++nt)
#pragma unroll
        for (int kq = 0; kq < 4; ++kq) {
            const float* p = W_ih + (long)(n0 + nt * 16 + l15) * I_ + kq * 32 + quad * 8;
            float4 lo = *(const float4*)(p);
            float4 hi = *(const float4*)(p + 4);
            short8 f;
            f[0] = f2bf(lo.x); f[1] = f2bf(lo.y); f[2] = f2bf(lo.z); f[3] = f2bf(lo.w);
            f[4] = f2bf(hi.x); f[5] = f2bf(hi.y); f[6] = f2bf(hi.z); f[7] = f2bf(hi.w);
            bfrag[nt][kq] = f;
        }

    short8 afrag[2][4];
#pragma unroll
    for (int mt = 0; mt < 2; ++mt)
#pragma unroll
        for (int kq = 0; kq < 4; ++kq) {
            const float* p = x + (m0 + mt * 16 + l15) * I_ + kq * 32 + quad * 8;
            float4 lo = *(const float4*)(p);
            float4 hi = *(const float4*)(p + 4);
            short8 f;
            f[0] = f2bf(lo.x); f[1] = f2bf(lo.y); f[2] = f2bf(lo.z); f[3] = f2bf(lo.w);
            f[4] = f2bf(hi.x); f[5] = f2bf(hi.y); f[6] = f2bf(hi.z); f[7] = f2bf(hi.w);
            afrag[mt][kq] = f;
        }

    floatx4 acc[2][8];
#pragma unroll
    for (int mt = 0; mt < 2; ++mt)
#pragma unroll
        for (int nt = 0; nt < 8; ++nt) acc[mt][nt] = (floatx4){0.f, 0.f, 0.f, 0.f};

#pragma unroll
    for (int kq = 0; kq < 4; ++kq)
#pragma unroll
        for (int mt = 0; mt < 2; ++mt)
#pragma unroll
            for (int nt = 0; nt < 8; ++nt)
                acc[mt][nt] = __builtin_amdgcn_mfma_f32_16x16x32_bf16(
                    afrag[mt][kq], bfrag[nt][kq], acc[mt][nt], 0, 0, 0);

    float biasv[8];
#pragma unroll
    for (int nt = 0; nt < 8; ++nt) {
        int n = n0 + nt * 16 + l15;
        biasv[nt] = b_ih[n] + b_hh[n];
    }
#pragma unroll
    for (int mt = 0; mt < 2; ++mt)
#pragma unroll
        for (int nt = 0; nt < 8; ++nt)
#pragma unroll
            for (int r = 0; r < 4; ++r) {
                long row = m0 + mt * 16 + quad * 4 + r;
                xp[row * H_ + n0 + nt * 16 + l15] = acc[mt][nt][r] + biasv[nt];
            }
}

// ---------------- Kernel B: MFMA recurrence, 8 blocks x 16 batches, 8 waves.
// LDS h layout: [buf][batch row=l15][256 cols], 16B-block swizzle c' = c ^ (l15&7).
__global__ __launch_bounds__(512, 2)
void rnn_kernel(const float* __restrict__ xp, const float* __restrict__ W_hh,
                const float* __restrict__ W_fc, const float* __restrict__ b_fc,
                float* __restrict__ out) {
    __shared__ __align__(16) short hbuf[2][16][256];
    const int tid  = threadIdx.x;
    const int wave = tid >> 6, lane = tid & 63;
    const int l15  = lane & 15, quad = lane >> 4;
    const int b0   = blockIdx.x * 16;
    const int n0   = wave * 32;
    const int swz  = l15 & 7;

    // W_hh A-fragments: fp32 load -> bf16, resident across all 512 steps
    short8 wfrag[2][8];
#pragma unroll
    for (int mt = 0; mt < 2; ++mt)
#pragma unroll
        for (int kq = 0; kq < 8; ++kq) {
            const float* p = W_hh + (long)(n0 + mt * 16 + l15) * H_ + kq * 32 + quad * 8;
            float4 lo = *(const float4*)(p);
            float4 hi = *(const float4*)(p + 4);
            short8 f;
            f[0] = f2bf(lo.x); f[1] = f2bf(lo.y); f[2] = f2bf(lo.z); f[3] = f2bf(lo.w);
            f[4] = f2bf(hi.x); f[5] = f2bf(hi.y); f[6] = f2bf(hi.z); f[7] = f2bf(hi.w);
            wfrag[mt][kq] = f;
        }

    // zero both h buffers (h_0 = 0)
    {
        int* hz = (int*)hbuf;
#pragma unroll
        for (int i = tid; i < 2 * 16 * 256 / 2; i += 512) hz[i] = 0;
    }
    __syncthreads();

    // swizzled read offsets (shorts): logical 16B-block c = quad + 4*kq
    int roff[8];
#pragma unroll
    for (int kq = 0; kq < 8; ++kq)
        roff[kq] = l15 * 256 + (((quad + 4 * kq) ^ swz) << 3);

    // swizzled write offsets (shorts): logical block c = wave*4 + 2*mt + (quad>>1), sub-8B = quad&1
    int woff[2];
#pragma unroll
    for (int mt = 0; mt < 2; ++mt) {
        int c = wave * 4 + 2 * mt + (quad >> 1);
        woff[mt] = l15 * 256 + ((c ^ swz) << 3) + (quad & 1) * 4;
    }

    const float* xpl = xp + (long)(b0 + l15) * T_ * H_ + n0 + quad * 4;
    float4 xvA[2], xvB[2];
#pragma unroll
    for (int mt = 0; mt < 2; ++mt) xvA[mt] = *(const float4*)(xpl + mt * 16);

    const short* rb0 = &hbuf[0][0][0];
    short*       wb0 = &hbuf[0][0][0];
    const short* rb1 = &hbuf[1][0][0];
    short*       wb1 = &hbuf[1][0][0];

#define BAR() asm volatile("s_waitcnt lgkmcnt(0)\n\ts_barrier" ::: "memory")

#define STEP(CUR, NXT, XV, XN, TPF)                                                     \
    {                                                                                   \
        /* prefetch xp for a future step (consumed next half) */                        \
        _Pragma("unroll")                                                               \
        for (int mt = 0; mt < 2; ++mt)                                                  \
            XN[mt] = *(const float4*)(xpl + (long)(TPF) * H_ + mt * 16);                \
        short8 hfrag[8];                                                                \
        _Pragma("unroll")                                                               \
        for (int kq = 0; kq < 8; ++kq)                                                  \
            hfrag[kq] = *(const short8*)((CUR) + roff[kq]);                             \
        floatx4 a0[2], a1[2];                                                           \
        _Pragma("unroll")                                                               \
        for (int mt = 0; mt < 2; ++mt) {                                                \
            a0[mt] = (floatx4){XV[mt].x, XV[mt].y, XV[mt].z, XV[mt].w};                 \
            a1[mt] = (floatx4){0.f, 0.f, 0.f, 0.f};                                     \
        }                                                                               \
        _Pragma("unroll")                                                               \
        for (int kq = 0; kq < 4; ++kq) {                                                \
            _Pragma("unroll")                                                           \
            for (int mt = 0; mt < 2; ++mt) {                                            \
                a0[mt] = __builtin_amdgcn_mfma_f32_16x16x32_bf16(                       \
                    wfrag[mt][kq], hfrag[kq], a0[mt], 0, 0, 0);                         \
                a1[mt] = __builtin_amdgcn_mfma_f32_16x16x32_bf16(                       \
                    wfrag[mt][kq + 4], hfrag[kq + 4], a1[mt], 0, 0, 0);                 \
            }                                                                           \
        }                                                                               \
        _Pragma("unroll")                                                               \
        for (int mt = 0; mt < 2; ++mt) {                                                \
            float r0 = tanh_fast(a0[mt][0] + a1[mt][0]);                                \
            float r1 = tanh_fast(a0[mt][1] + a1[mt][1]);                                \
            float r2 = tanh_fast(a0[mt][2] + a1[mt][2]);                                \
            float r3 = tanh_fast(a0[mt][3] + a1[mt][3]);                                \
            __hip_bfloat162 q01 = __float22bfloat162_rn(float2{r0, r1});                \
            __hip_bfloat162 q23 = __float22bfloat162_rn(float2{r2, r3});                \
            int2 wv;                                                                    \
            wv.x = *(int*)&q01;                                                         \
            wv.y = *(int*)&q23;                                                         \
            *(int2*)((NXT) + woff[mt]) = wv;                                            \
        }                                                                               \
        BAR();                                                                          \
    }

#pragma unroll 1
    for (int t = 0; t < T_; t += 2) {
        const int t1 = (t + 1 < T_) ? t + 1 : T_ - 1;
        const int t2 = (t + 2 < T_) ? t + 2 : T_ - 1;
        STEP(rb0, wb1, xvA, xvB, t1);   // step t:   read buf0, write buf1
        STEP(rb1, wb0, xvB, xvA, t2);   // step t+1: read buf1, write buf0
    }
#undef STEP
#undef BAR

    // head: out[b] = sigmoid(b_fc + sum_n h_T[b][n] * W_fc[n]); h_T in buf[0] (swizzled)
    if (tid < 256) {
        const int bl = tid >> 4, seg = tid & 15;
        const int bswz = bl & 7;
        float p = 0.0f;
#pragma unroll
        for (int half = 0; half < 2; ++half) {
            const int c = 2 * seg + half;
            const short* hr = &hbuf[0][0][0] + bl * 256 + ((c ^ bswz) << 3);
#pragma unroll
            for (int i = 0; i < 8; ++i) {
                __hip_bfloat16 hv = *(const __hip_bfloat16*)(hr + i);
                p += __bfloat162float(hv) * W_fc[c * 8 + i];
            }
        }
#pragma unroll
        for (int off = 1; off < 16; off <<= 1) p += __shfl_xor(p, off);
        if (seg == 0) out[b0 + bl] = 1.0f / (1.0f + __expf(-(p + b_fc[0])));
    }
}

extern "C" void kernel_launch(void* const* d_in, const int* in_sizes, int n_in,
                              void* d_out, int out_size, void* d_ws, size_t ws_size,
                              hipStream_t stream) {
    const float* x    = (const float*)d_in[0];
    const float* W_ih = (const float*)d_in[1];
    const float* W_hh = (const float*)d_in[2];
    const float* b_ih = (const float*)d_in[3];
    const float* b_hh = (const float*)d_in[4];
    const float* W_fc = (const float*)d_in[5];
    const float* b_fc = (const float*)d_in[6];
    float* out = (float*)d_out;

    float* xp = (float*)d_ws;   // B*T*H fp32 = 67.1 MB

    xp_mfma_kernel<<<(B_ * T_) / 64, 256, 0, stream>>>(x, W_ih, b_ih, b_hh, xp);
    rnn_kernel<<<B_ / 16, 512, 0, stream>>>(xp, W_hh, W_fc, b_fc, out);
}

// Round 4
// 482.682 us; speedup vs baseline: 1.3999x; 1.1011x over previous
//
#include <hip/hip_runtime.h>
#include <hip/hip_bf16.h>

// B=128, T=512, I=128, H=256, O=1 (fp32 in/out)
// FULLY FUSED single kernel (R4 = R3 structure, hazard-safe epilogue):
//   v = S*(bias + W_ih·x_t + W_hh·h_t) accumulated in MFMA (S = 2*log2e),
//   h = 1 - 2*rcp(exp2(v)+1)   (exactly tanh)
// R3 failed (absmax 0.5): raw inline-asm v_exp_f32 read MFMA accumulators
// without the required MFMA->VALU wait-states (INLINEASM is not isVALU, so
// the hazard recognizer inserts no s_nops). R4 uses __builtin_amdgcn_exp2f /
// __builtin_amdgcn_rcpf — same instructions, compiler-managed hazards.
// Pipeline per step t (one barrier per step):
//   global-load x_{t+3} (reg) | ds_write x_{t+2} (bf16, swizzled) |
//   ds_read h_t + x_{t+1} frags | 16 h-MFMA + 8 x-MFMA (a_next seeded w/ bias') |
//   tanh epilogue -> ds_write h_{t+1} | BAR

#define B_ 128
#define T_ 512
#define I_ 128
#define H_ 256
#define SCALE 2.8853900817779268f   // 2*log2(e)

typedef __attribute__((ext_vector_type(8))) short short8;
typedef __attribute__((ext_vector_type(4))) float floatx4;

__device__ __forceinline__ short8 pack8(float4 lo, float4 hi) {
    __hip_bfloat162 p0 = __float22bfloat162_rn(float2{lo.x, lo.y});
    __hip_bfloat162 p1 = __float22bfloat162_rn(float2{lo.z, lo.w});
    __hip_bfloat162 p2 = __float22bfloat162_rn(float2{hi.x, hi.y});
    __hip_bfloat162 p3 = __float22bfloat162_rn(float2{hi.z, hi.w});
    int4 i;
    i.x = *(int*)&p0; i.y = *(int*)&p1; i.z = *(int*)&p2; i.w = *(int*)&p3;
    return *(short8*)&i;
}
__device__ __forceinline__ short8 pack8s(float4 lo, float4 hi, float s) {
    lo.x *= s; lo.y *= s; lo.z *= s; lo.w *= s;
    hi.x *= s; hi.y *= s; hi.z *= s; hi.w *= s;
    return pack8(lo, hi);
}
// tanh(z) where v = 2*log2e*z is the prescaled MFMA result.
// Builtins (not asm) so MFMA->VALU hazards are compiler-handled.
__device__ __forceinline__ float tanh_s(float v) {
    float e = __builtin_amdgcn_exp2f(v);          // 2^v = exp(2z)
    float r = __builtin_amdgcn_rcpf(e + 1.0f);
    return __builtin_fmaf(-2.0f, r, 1.0f);        // 1 - 2/(e+1)
}

__global__ __launch_bounds__(512, 2)
void rnn_fused(const float* __restrict__ x, const float* __restrict__ W_ih,
               const float* __restrict__ W_hh, const float* __restrict__ b_ih,
               const float* __restrict__ b_hh, const float* __restrict__ W_fc,
               const float* __restrict__ b_fc, float* __restrict__ out) {
    __shared__ __align__(16) short hbuf[2][16][256];   // h_t bf16, 16B-XOR swizzled
    __shared__ __align__(16) short xbuf[2][16][128];   // x_t bf16, 16B-XOR swizzled
    const int tid  = threadIdx.x;
    const int wave = tid >> 6, lane = tid & 63;
    const int l15  = lane & 15, quad = lane >> 4;
    const int b0   = blockIdx.x * 16;
    const int n0   = wave * 32;
    const int swz  = l15 & 7;

    // resident W_hh' fragments (prescaled)
    short8 wfrag[2][8];
#pragma unroll
    for (int mt = 0; mt < 2; ++mt)
#pragma unroll
        for (int kq = 0; kq < 8; ++kq) {
            const float* p = W_hh + (long)(n0 + mt * 16 + l15) * H_ + kq * 32 + quad * 8;
            wfrag[mt][kq] = pack8s(*(const float4*)p, *(const float4*)(p + 4), SCALE);
        }
    // resident W_ih' fragments (prescaled)
    short8 wih[2][4];
#pragma unroll
    for (int mt = 0; mt < 2; ++mt)
#pragma unroll
        for (int kq = 0; kq < 4; ++kq) {
            const float* p = W_ih + (long)(n0 + mt * 16 + l15) * I_ + kq * 32 + quad * 8;
            wih[mt][kq] = pack8s(*(const float4*)p, *(const float4*)(p + 4), SCALE);
        }
    // prescaled bias per output element: n = n0 + mt*16 + quad*4 + r
    floatx4 bias2[2];
#pragma unroll
    for (int mt = 0; mt < 2; ++mt)
#pragma unroll
        for (int r = 0; r < 4; ++r) {
            int n = n0 + mt * 16 + quad * 4 + r;
            bias2[mt][r] = SCALE * (b_ih[n] + b_hh[n]);
        }

    // zero hbuf[0] (h_0 = 0)
    {
        int* hz = (int*)&hbuf[0][0][0];
#pragma unroll
        for (int i = tid; i < 16 * 256 / 2; i += 512) hz[i] = 0;
    }

    // x staging: thread (sb=batch, sj=4-float chunk), 8B-granule swizzle sj^((sb&7)<<1)
    const int sb = tid >> 5, sj = tid & 31;
    const float* xsrc = x + (long)(b0 + sb) * T_ * I_ + sj * 4;
    const int xwoff = sb * 128 + ((sj ^ ((sb & 7) << 1)) << 2);
    {   // stage x_1 -> xbuf[1]
        float4 s1 = *(const float4*)(xsrc + I_);
        __hip_bfloat162 q0 = __float22bfloat162_rn(float2{s1.x, s1.y});
        __hip_bfloat162 q1 = __float22bfloat162_rn(float2{s1.z, s1.w});
        int2 sw; sw.x = *(int*)&q0; sw.y = *(int*)&q1;
        *(int2*)(&xbuf[1][0][0] + xwoff) = sw;
    }
    float4 xhA = *(const float4*)(xsrc + 2 * I_);   // x_2, written during step 0
    float4 xhB;

    // LDS read offsets (shorts)
    int roff[8];
#pragma unroll
    for (int kq = 0; kq < 8; ++kq)
        roff[kq] = l15 * 256 + (((quad + 4 * kq) ^ swz) << 3);
    int xroff[4];
#pragma unroll
    for (int kq = 0; kq < 4; ++kq)
        xroff[kq] = l15 * 128 + (((kq * 4 + quad) ^ swz) << 3);
    int woff[2];
#pragma unroll
    for (int mt = 0; mt < 2; ++mt) {
        int c = wave * 4 + 2 * mt + (quad >> 1);
        woff[mt] = l15 * 256 + ((c ^ swz) << 3) + (quad & 1) * 4;
    }

    // prolog: aA = bias' + W_ih'·x_0 (x_0 direct from global)
    floatx4 aA[2], aB[2];
    {
        short8 xf[4];
#pragma unroll
        for (int kq = 0; kq < 4; ++kq) {
            const float* p = x + (long)(b0 + l15) * T_ * I_ + kq * 32 + quad * 8;
            xf[kq] = pack8(*(const float4*)p, *(const float4*)(p + 4));
        }
#pragma unroll
        for (int mt = 0; mt < 2; ++mt) aA[mt] = bias2[mt];
#pragma unroll
        for (int kq = 0; kq < 4; ++kq)
#pragma unroll
            for (int mt = 0; mt < 2; ++mt)
                aA[mt] = __builtin_amdgcn_mfma_f32_16x16x32_bf16(
                    wih[mt][kq], xf[kq], aA[mt], 0, 0, 0);
    }
    __syncthreads();   // staging + zero visible before step 0

    const short* hb0r = &hbuf[0][0][0]; short* hb0w = &hbuf[0][0][0];
    const short* hb1r = &hbuf[1][0][0]; short* hb1w = &hbuf[1][0][0];
    const short* xb0r = &xbuf[0][0][0]; short* xb0w = &xbuf[0][0][0];
    const short* xb1r = &xbuf[1][0][0]; short* xb1w = &xbuf[1][0][0];

#define BAR() asm volatile("s_waitcnt lgkmcnt(0)\n\ts_barrier" ::: "memory")

#define STEP(HR, HW, XR, XW, ACUR, ANXT, XH, XN, TLD)                           \
    {                                                                           \
        XN = *(const float4*)(xsrc + (long)(TLD) * I_);                         \
        {                                                                       \
            __hip_bfloat162 q0 = __float22bfloat162_rn(float2{XH.x, XH.y});     \
            __hip_bfloat162 q1 = __float22bfloat162_rn(float2{XH.z, XH.w});     \
            int2 sw; sw.x = *(int*)&q0; sw.y = *(int*)&q1;                      \
            *(int2*)((XW) + xwoff) = sw;                                        \
        }                                                                       \
        short8 hfrag[8];                                                        \
        _Pragma("unroll")                                                       \
        for (int kq = 0; kq < 8; ++kq)                                          \
            hfrag[kq] = *(const short8*)((HR) + roff[kq]);                      \
        short8 xfrag[4];                                                        \
        _Pragma("unroll")                                                       \
        for (int kq = 0; kq < 4; ++kq)                                          \
            xfrag[kq] = *(const short8*)((XR) + xroff[kq]);                     \
        _Pragma("unroll")                                                       \
        for (int kq = 0; kq < 8; ++kq)                                          \
            _Pragma("unroll")                                                   \
            for (int mt = 0; mt < 2; ++mt)                                      \
                ACUR[mt] = __builtin_amdgcn_mfma_f32_16x16x32_bf16(             \
                    wfrag[mt][kq], hfrag[kq], ACUR[mt], 0, 0, 0);               \
        _Pragma("unroll")                                                       \
        for (int mt = 0; mt < 2; ++mt) ANXT[mt] = bias2[mt];                    \
        _Pragma("unroll")                                                       \
        for (int kq = 0; kq < 4; ++kq)                                          \
            _Pragma("unroll")                                                   \
            for (int mt = 0; mt < 2; ++mt)                                      \
                ANXT[mt] = __builtin_amdgcn_mfma_f32_16x16x32_bf16(             \
                    wih[mt][kq], xfrag[kq], ANXT[mt], 0, 0, 0);                 \
        _Pragma("unroll")                                                       \
        for (int mt = 0; mt < 2; ++mt) {                                        \
            float r0 = tanh_s(ACUR[mt][0]);                                     \
            float r1 = tanh_s(ACUR[mt][1]);                                     \
            float r2 = tanh_s(ACUR[mt][2]);                                     \
            float r3 = tanh_s(ACUR[mt][3]);                                     \
            __hip_bfloat162 q01 = __float22bfloat162_rn(float2{r0, r1});        \
            __hip_bfloat162 q23 = __float22bfloat162_rn(float2{r2, r3});        \
            int2 wv; wv.x = *(int*)&q01; wv.y = *(int*)&q23;                    \
            *(int2*)((HW) + woff[mt]) = wv;                                     \
        }                                                                       \
        BAR();                                                                  \
    }

#pragma unroll 1
    for (int t = 0; t < T_; t += 2) {
        const int tl0 = (t + 3 < T_) ? t + 3 : T_ - 1;
        const int tl1 = (t + 4 < T_) ? t + 4 : T_ - 1;
        STEP(hb0r, hb1w, xb1r, xb0w, aA, aB, xhA, xhB, tl0);   // even t
        STEP(hb1r, hb0w, xb0r, xb1w, aB, aA, xhB, xhA, tl1);   // odd t
    }
#undef STEP
#undef BAR

    // head: out[b] = sigmoid(b_fc + sum_n h_T[b][n] * W_fc[n]); h_T in hbuf[0] (swizzled)
    if (tid < 256) {
        const int bl = tid >> 4, seg = tid & 15;
        const int bswz = bl & 7;
        float p = 0.0f;
#pragma unroll
        for (int half = 0; half < 2; ++half) {
            const int c = 2 * seg + half;
            const short* hr = &hbuf[0][0][0] + bl * 256 + ((c ^ bswz) << 3);
#pragma unroll
            for (int i = 0; i < 8; ++i) {
                __hip_bfloat16 hv = *(const __hip_bfloat16*)(hr + i);
                p += __bfloat162float(hv) * W_fc[c * 8 + i];
            }
        }
#pragma unroll
        for (int off = 1; off < 16; off <<= 1) p += __shfl_xor(p, off);
        if (seg == 0) out[b0 + bl] = 1.0f / (1.0f + __expf(-(p + b_fc[0])));
    }
}

extern "C" void kernel_launch(void* const* d_in, const int* in_sizes, int n_in,
                              void* d_out, int out_size, void* d_ws, size_t ws_size,
                              hipStream_t stream) {
    const float* x    = (const float*)d_in[0];
    const float* W_ih = (const float*)d_in[1];
    const float* W_hh = (const float*)d_in[2];
    const float* b_ih = (const float*)d_in[3];
    const float* b_hh = (const float*)d_in[4];
    const float* W_fc = (const float*)d_in[5];
    const float* b_fc = (const float*)d_in[6];
    float* out = (float*)d_out;
    (void)d_ws; (void)ws_size;   // workspace no longer needed

    rnn_fused<<<B_ / 16, 512, 0, stream>>>(x, W_ih, W_hh, b_ih, b_hh, W_fc, b_fc, out);
}